// Round 4
// baseline (232.706 us; speedup 1.0000x reference)
//
#include <hip/hip_runtime.h>
#include <math.h>

namespace {

constexpr int B = 4;
constexpr int C = 512;
constexpr int NH = 32;          // heads
constexpr int CPH = 16;         // channels per head
constexpr int N = 32 * 32 * 32; // 32768 spatial
constexpr int SCH = 2;          // sub-chunks (of 1024 n) per kA block
constexpr int NPART = 64;       // partials per (b,h): 16 blocks x 4 waves
constexpr long YSIZE = (long)B * C * N;  // 67,108,864

__device__ inline float wrs(float v) {
#pragma unroll
  for (int o = 32; o > 0; o >>= 1) v += __shfl_xor(v, o);
  return v;
}

// ---------------------------------------------------------------------------
// kA: single HBM pass over x. grid (16, NH, B) = 2048 blocks, 256 threads.
// Each block: 2048 consecutive n of one (b,h) group (16 channels).
// Per sub-chunk (1024 n): phase A streams the 16 channel loads directly into
// the K/Q logit FMAs (x consumed immediately; also accumulates plain channel
// sums for mu), computes exp. Phase B RE-READS the same cache-resident lines
// (L1/L2; an asm memory clobber blocks CSE so no 64-VGPR tile is kept) and
// accumulates the exp-weighted sums. No max-shift (logits ~unit variance;
// fp32 exp overflows only past 88). Biases & -mu*w cancel in softmax;
// sum_n attn = 1 folds mean subtraction into k4. One wave-level merge at the
// end -> per-wave partials. No LDS, no barriers.
__global__ __launch_bounds__(256) void kA(const float* __restrict__ x,
                                          const float* __restrict__ kw,
                                          const float* __restrict__ qw,
                                          float* __restrict__ psK,
                                          float* __restrict__ psQ,
                                          float* __restrict__ pdK,
                                          float* __restrict__ pdQ,
                                          float* __restrict__ pcs) {
  const int b = blockIdx.z, h = blockIdx.y, j = blockIdx.x;
  const int t = threadIdx.x, lane = t & 63, wid = t >> 6;
  const float* xb = x + ((long)(b * C + h * CPH)) * N + (long)j * (SCH * 1024) + t * 4;

  float wk[CPH], wq[CPH];  // wave-uniform (blockIdx-derived) -> scalar loads
#pragma unroll
  for (int c = 0; c < CPH; ++c) {
    wk[c] = kw[h * CPH + c];
    wq[c] = qw[h * CPH + c];
  }

  float dK[CPH], dQ[CPH], cs[CPH];
  float sK = 0.f, sQ = 0.f;
#pragma unroll
  for (int c = 0; c < CPH; ++c) { dK[c] = 0.f; dQ[c] = 0.f; cs[c] = 0.f; }

  for (int s = 0; s < SCH; ++s) {
    const float* xs = xb + s * 1024;
    // phase A: logits + channel sums (x not retained)
    float4 lk = make_float4(0.f, 0.f, 0.f, 0.f);
    float4 lq = make_float4(0.f, 0.f, 0.f, 0.f);
#pragma unroll
    for (int c = 0; c < CPH; ++c) {
      const float4 xv = *(const float4*)(xs + (long)c * N);
      lk.x += xv.x * wk[c]; lk.y += xv.y * wk[c];
      lk.z += xv.z * wk[c]; lk.w += xv.w * wk[c];
      lq.x += xv.x * wq[c]; lq.y += xv.y * wq[c];
      lq.z += xv.z * wq[c]; lq.w += xv.w * wq[c];
      cs[c] += (xv.x + xv.y) + (xv.z + xv.w);
    }
    const float4 ek = make_float4(__expf(lk.x), __expf(lk.y),
                                  __expf(lk.z), __expf(lk.w));
    const float4 eq = make_float4(__expf(lq.x), __expf(lq.y),
                                  __expf(lq.z), __expf(lq.w));
    sK += (ek.x + ek.y) + (ek.z + ek.w);
    sQ += (eq.x + eq.y) + (eq.z + eq.w);
    // block CSE of the phase-B reloads (they hit L1/L2)
    asm volatile("" ::: "memory");
    // phase B: exp-weighted accumulation (re-read, cache-hot)
#pragma unroll
    for (int c = 0; c < CPH; ++c) {
      const float4 xv = *(const float4*)(xs + (long)c * N);
      dK[c] += (xv.x * ek.x + xv.y * ek.y) + (xv.z * ek.z + xv.w * ek.w);
      dQ[c] += (xv.x * eq.x + xv.y * eq.y) + (xv.z * eq.z + xv.w * eq.w);
    }
  }

  // one wave-level merge; per-wave partial index
  const long pj = ((long)(b * NH + h)) * NPART + j * 4 + wid;
  float v;
  v = wrs(sK); if (lane == 0) psK[pj] = v;
  v = wrs(sQ); if (lane == 0) psQ[pj] = v;
#pragma unroll
  for (int c = 0; c < CPH; ++c) {
    v = wrs(dK[c]); if (lane == 0) pdK[pj * CPH + c] = v;
    v = wrs(dQ[c]); if (lane == 0) pdQ[pj * CPH + c] = v;
    v = wrs(cs[c]); if (lane == 0) pcs[pj * CPH + c] = v;
  }
}

// ---------------------------------------------------------------------------
// k4: combine partials + finalize. grid(B), 512 threads (thread = channel).
__global__ __launch_bounds__(512) void k4(const float* __restrict__ psK,
                                          const float* __restrict__ psQ,
                                          const float* __restrict__ pdK,
                                          const float* __restrict__ pdQ,
                                          const float* __restrict__ pcs,
                                          const float* __restrict__ pw1,
                                          const float* __restrict__ pb1,
                                          const float* __restrict__ pw2,
                                          const float* __restrict__ pb2,
                                          float* __restrict__ scale,
                                          float* __restrict__ offset,
                                          float* __restrict__ dpOut) {
  const int b = blockIdx.x;
  const int c = threadIdx.x;           // 0..511
  const int h = c >> 4, i = c & 15;
  const long base = (long)(b * NH + h) * NPART;

  float sk = 0.f, sq = 0.f, dk = 0.f, dq = 0.f, cs = 0.f;
  for (int j = 0; j < NPART; ++j) {
    sk += psK[base + j];
    sq += psQ[base + j];
    dk += pdK[(base + j) * CPH + i];
    dq += pdQ[(base + j) * CPH + i];
    cs += pcs[(base + j) * CPH + i];
  }
  const float mu = cs * (1.f / N);
  const float Kv = dk / sk - mu;
  const float Qv = dq / sq - mu;

  __shared__ float muS[C], h1S[256];
  muS[c] = mu;
  __syncthreads();
  if (c < 256) {
    const int g = c >> 3;
    float a = pb1[c];
#pragma unroll
    for (int k = 0; k < 16; ++k) a += muS[g * 16 + k] * pw1[c * 16 + k];
    h1S[c] = fmaxf(a, 0.f);
  }
  __syncthreads();
  float a = pb2[c];
  const int g2 = c >> 4;
#pragma unroll
  for (int k = 0; k < 8; ++k) a += h1S[g2 * 8 + k] * pw2[c * 8 + k];
  const float P = 1.f / (1.f + __expf(-a));
  scale[b * C + c] = P;
  offset[b * C + c] = (Kv - Qv) * P;

  float p = wrs(Kv * Qv);
  __shared__ float pS[8];
  const int lane = c & 63, wid = c >> 6;
  if (lane == 0) pS[wid] = p;
  __syncthreads();
  if (c == 0) {
    float tot = 0.f;
    for (int w = 0; w < 8; ++w) tot += pS[w];
    dpOut[b] = tot * (1.f / C);
  }
}

// ---------------------------------------------------------------------------
// k5: y = x * scale[b,c] + offset[b,c]. grid (N/4096, C, B), block 256.
__global__ __launch_bounds__(256) void k5(const float* __restrict__ x,
                                          const float* __restrict__ scale,
                                          const float* __restrict__ offset,
                                          float* __restrict__ y) {
  const int b = blockIdx.z, cc = blockIdx.y;
  const int t = threadIdx.x;
  const long base = ((long)(b * C + cc)) * N + (long)blockIdx.x * 4096;
  const float s = scale[b * C + cc], o = offset[b * C + cc];
#pragma unroll
  for (int k = 0; k < 4; ++k) {
    const long i = base + (long)(k * 256 + t) * 4;
    float4 v = *(const float4*)(x + i);
    v.x = v.x * s + o; v.y = v.y * s + o;
    v.z = v.z * s + o; v.w = v.w * s + o;
    *(float4*)(y + i) = v;
  }
}

} // namespace

extern "C" void kernel_launch(void* const* d_in, const int* in_sizes, int n_in,
                              void* d_out, int out_size, void* d_ws, size_t ws_size,
                              hipStream_t stream) {
  const float* x   = (const float*)d_in[0];
  const float* pw1 = (const float*)d_in[1];
  const float* pb1 = (const float*)d_in[2];
  const float* pw2 = (const float*)d_in[3];
  const float* pb2 = (const float*)d_in[4];
  const float* kw  = (const float*)d_in[5];
  // d_in[6]=kb, d_in[8]=qb unused: biases cancel in softmax (shift-invariant),
  // and sum_n attn = 1 folds mean-subtraction into the finalize step.
  const float* qw  = (const float*)d_in[7];
  float* out = (float*)d_out;
  float* ws  = (float*)d_ws;

  // scale/offset always in ws (read by k5 while k5 writes out)
  float* scale  = ws;          // 2048
  float* offset = ws + 2048;   // 2048

  // partials: 2*8192 + 3*131072 = 409600 floats (~1.6 MB)
  constexpr long PM = (long)B * NH * NPART;    // 8192
  constexpr long PD = PM * CPH;                // 131072
  constexpr long partialFloats = 2 * PM + 3 * PD;
  float* pbase;
  if (ws_size >= (size_t)(4096 + partialFloats) * sizeof(float)) {
    pbase = ws + 4096;
  } else {
    pbase = out;  // consumed by k4 before k5 overwrites out
  }
  float* psK = pbase;
  float* psQ = pbase + PM;
  float* pdK = pbase + 2 * PM;
  float* pdQ = pbase + 2 * PM + PD;
  float* pcs = pbase + 2 * PM + 2 * PD;

  hipLaunchKernelGGL(kA, dim3(N / (SCH * 1024), NH, B), dim3(256), 0, stream,
                     x, kw, qw, psK, psQ, pdK, pdQ, pcs);
  hipLaunchKernelGGL(k4, dim3(B), dim3(C), 0, stream,
                     psK, psQ, pdK, pdQ, pcs,
                     pw1, pb1, pw2, pb2, scale, offset, out + YSIZE);
  hipLaunchKernelGGL(k5, dim3(N / 4096, C, B), dim3(256), 0, stream,
                     x, scale, offset, out);
}

// Round 6
// 180.080 us; speedup vs baseline: 1.2922x; 1.2922x over previous
//
#include <hip/hip_runtime.h>
#include <math.h>

namespace {

constexpr int B = 4;
constexpr int C = 512;
constexpr int NH = 32;          // heads
constexpr int CPH = 16;         // channels per head
constexpr int N = 32 * 32 * 32; // 32768 spatial
constexpr int NPW = 128;        // partial records per (b,h): 32 blocks x 4 waves
constexpr long YSIZE = (long)B * C * N;  // 67,108,864

__device__ inline float wrs(float v) {
#pragma unroll
  for (int o = 32; o > 0; o >>= 1) v += __shfl_xor(v, o);
  return v;
}

// ---------------------------------------------------------------------------
// kA: single HBM pass over x. grid (32, NH, B) = 4096 blocks, 256 threads.
// Block = 1024 consecutive n of one (b,h). All 16 channel float4 loads are
// issued as one independent batch into a register tile (16 KB/wave in flight
// -> latency hidden), then: logits (no max-shift: ~unit variance, fp32 exp
// safe to 88), exp, weighted sums. Merge: per value a FULL 64-lane butterfly
// (6 xor steps — R5's 2-step version summed only 4 lanes: wrong); lane c
// keeps dK[c], lane 16+c keeps dQ[c], lane 32+c keeps cs[c], lanes 48/49
// keep sK/sQ -> ONE coalesced 64-float record store per wave. xv[c] dies at
// merge iteration c, keeping peak VGPR ~100. No LDS, no barriers. Biases &
// -mu*w cancel in softmax; sum_n attn = 1 folds mean subtraction into k4.
__global__ __launch_bounds__(256, 4) void kA(const float* __restrict__ x,
                                             const float* __restrict__ kw,
                                             const float* __restrict__ qw,
                                             float* __restrict__ prec) {
  const int b = blockIdx.z, h = blockIdx.y, j = blockIdx.x;
  const int t = threadIdx.x, lane = t & 63, wid = t >> 6;
  const float* xs = x + ((long)(b * C + h * CPH)) * N + (long)j * 1024 + t * 4;

  // batched independent loads -> register tile
  float4 xv[CPH];
#pragma unroll
  for (int c = 0; c < CPH; ++c) xv[c] = *(const float4*)(xs + (long)c * N);

  float4 lk = make_float4(0.f, 0.f, 0.f, 0.f);
  float4 lq = make_float4(0.f, 0.f, 0.f, 0.f);
#pragma unroll
  for (int c = 0; c < CPH; ++c) {
    const float wkc = kw[h * CPH + c], wqc = qw[h * CPH + c];
    lk.x += xv[c].x * wkc; lk.y += xv[c].y * wkc;
    lk.z += xv[c].z * wkc; lk.w += xv[c].w * wkc;
    lq.x += xv[c].x * wqc; lq.y += xv[c].y * wqc;
    lq.z += xv[c].z * wqc; lq.w += xv[c].w * wqc;
  }
  const float4 ek = make_float4(__expf(lk.x), __expf(lk.y),
                                __expf(lk.z), __expf(lk.w));
  const float4 eq = make_float4(__expf(lq.x), __expf(lq.y),
                                __expf(lq.z), __expf(lq.w));
  float sK = wrs((ek.x + ek.y) + (ek.z + ek.w));
  float sQ = wrs((eq.x + eq.y) + (eq.z + eq.w));

  float outv = 0.f;
#pragma unroll
  for (int c = 0; c < CPH; ++c) {
    float dk = (xv[c].x * ek.x + xv[c].y * ek.y) + (xv[c].z * ek.z + xv[c].w * ek.w);
    float dq = (xv[c].x * eq.x + xv[c].y * eq.y) + (xv[c].z * eq.z + xv[c].w * eq.w);
    float cs = (xv[c].x + xv[c].y) + (xv[c].z + xv[c].w);
    dk = wrs(dk);   // full 64-lane sum
    dq = wrs(dq);
    cs = wrs(cs);
    if (lane == c)      outv = dk;
    if (lane == c + 16) outv = dq;
    if (lane == c + 32) outv = cs;
  }
  if (lane == 48) outv = sK;
  if (lane == 49) outv = sQ;

  const long pj = ((long)(b * NH + h)) * NPW + j * 4 + wid;
  prec[pj * 64 + lane] = outv;
}

// ---------------------------------------------------------------------------
// k4: combine partial records + finalize. grid(B), 512 threads (thread=channel).
__global__ __launch_bounds__(512) void k4(const float* __restrict__ prec,
                                          const float* __restrict__ pw1,
                                          const float* __restrict__ pb1,
                                          const float* __restrict__ pw2,
                                          const float* __restrict__ pb2,
                                          float* __restrict__ scale,
                                          float* __restrict__ offset,
                                          float* __restrict__ dpOut) {
  const int b = blockIdx.x;
  const int c = threadIdx.x;           // 0..511
  const int h = c >> 4, i = c & 15;
  const float* rec = prec + ((long)(b * NH + h)) * NPW * 64;

  float dk = 0.f, dq = 0.f, cs = 0.f, sk = 0.f, sq = 0.f;
  for (int j = 0; j < NPW; ++j) {
    dk += rec[j * 64 + i];
    dq += rec[j * 64 + 16 + i];
    cs += rec[j * 64 + 32 + i];
    sk += rec[j * 64 + 48];
    sq += rec[j * 64 + 49];
  }
  const float mu = cs * (1.f / N);
  const float Kv = dk / sk - mu;
  const float Qv = dq / sq - mu;

  __shared__ float muS[C], h1S[256];
  muS[c] = mu;
  __syncthreads();
  if (c < 256) {
    const int g = c >> 3;
    float a = pb1[c];
#pragma unroll
    for (int k = 0; k < 16; ++k) a += muS[g * 16 + k] * pw1[c * 16 + k];
    h1S[c] = fmaxf(a, 0.f);
  }
  __syncthreads();
  float a = pb2[c];
  const int g2 = c >> 4;
#pragma unroll
  for (int k = 0; k < 8; ++k) a += h1S[g2 * 8 + k] * pw2[c * 8 + k];
  const float P = 1.f / (1.f + __expf(-a));
  scale[b * C + c] = P;
  offset[b * C + c] = (Kv - Qv) * P;

  float p = wrs(Kv * Qv);
  __shared__ float pS[8];
  const int lane = c & 63, wid = c >> 6;
  if (lane == 0) pS[wid] = p;
  __syncthreads();
  if (c == 0) {
    float tot = 0.f;
    for (int w = 0; w < 8; ++w) tot += pS[w];
    dpOut[b] = tot * (1.f / C);
  }
}

// ---------------------------------------------------------------------------
// k5: y = x * scale[b,c] + offset[b,c]. grid (N/4096, C, B), block 256.
__global__ __launch_bounds__(256) void k5(const float* __restrict__ x,
                                          const float* __restrict__ scale,
                                          const float* __restrict__ offset,
                                          float* __restrict__ y) {
  const int b = blockIdx.z, cc = blockIdx.y;
  const int t = threadIdx.x;
  const long base = ((long)(b * C + cc)) * N + (long)blockIdx.x * 4096;
  const float s = scale[b * C + cc], o = offset[b * C + cc];
#pragma unroll
  for (int k = 0; k < 4; ++k) {
    const long i = base + (long)(k * 256 + t) * 4;
    float4 v = *(const float4*)(x + i);
    v.x = v.x * s + o; v.y = v.y * s + o;
    v.z = v.z * s + o; v.w = v.w * s + o;
    *(float4*)(y + i) = v;
  }
}

} // namespace

extern "C" void kernel_launch(void* const* d_in, const int* in_sizes, int n_in,
                              void* d_out, int out_size, void* d_ws, size_t ws_size,
                              hipStream_t stream) {
  const float* x   = (const float*)d_in[0];
  const float* pw1 = (const float*)d_in[1];
  const float* pb1 = (const float*)d_in[2];
  const float* pw2 = (const float*)d_in[3];
  const float* pb2 = (const float*)d_in[4];
  const float* kw  = (const float*)d_in[5];
  // d_in[6]=kb, d_in[8]=qb unused: biases cancel in softmax (shift-invariant),
  // and sum_n attn = 1 folds mean-subtraction into the finalize step.
  const float* qw  = (const float*)d_in[7];
  float* out = (float*)d_out;
  float* ws  = (float*)d_ws;

  // scale/offset always in ws (read by k5 while k5 writes out)
  float* scale  = ws;          // 2048
  float* offset = ws + 2048;   // 2048

  // partial records: B*NH*NPW*64 = 1,048,576 floats (4 MB)
  constexpr long PREC = (long)B * NH * NPW * 64;
  float* prec;
  if (ws_size >= (size_t)(4096 + PREC) * sizeof(float)) {
    prec = ws + 4096;
  } else {
    prec = out;  // consumed by k4 before k5 overwrites out
  }

  hipLaunchKernelGGL(kA, dim3(N / 1024, NH, B), dim3(256), 0, stream,
                     x, kw, qw, prec);
  hipLaunchKernelGGL(k4, dim3(B), dim3(C), 0, stream,
                     prec, pw1, pb1, pw2, pb2, scale, offset, out + YSIZE);
  hipLaunchKernelGGL(k5, dim3(N / 4096, C, B), dim3(256), 0, stream,
                     x, scale, offset, out);
}

// Round 7
// 150.292 us; speedup vs baseline: 1.5484x; 1.1982x over previous
//
#include <hip/hip_runtime.h>
#include <math.h>

namespace {

constexpr int B = 4;
constexpr int C = 512;
constexpr int NH = 32;          // heads
constexpr int CPH = 16;         // channels per head
constexpr int N = 32 * 32 * 32; // 32768 spatial
constexpr int NPW = 128;        // partial records per (b,h): 32 blocks x 4 waves
constexpr long YSIZE = (long)B * C * N;  // 67,108,864

typedef float f4v __attribute__((ext_vector_type(4)));

__device__ inline float wrs(float v) {
#pragma unroll
  for (int o = 32; o > 0; o >>= 1) v += __shfl_xor(v, o);
  return v;
}

// DPP-based wave sum: 4 intra-row steps on the VALU pipe (quad_perm xor1,
// xor2; row_ror 4, 8 -> every lane holds its 16-lane row sum), then only 2
// cross-row steps on the LDS/crossbar pipe. Replaces the 6-step shfl
// butterfly (which put ALL 6 steps on the LDS pipe via ds_bpermute/swizzle).
template <int CTRL>
__device__ __forceinline__ float dppAdd(float v) {
  const int r = __builtin_amdgcn_update_dpp(
      0, __float_as_int(v), CTRL, 0xF, 0xF, true);
  return v + __int_as_float(r);
}
__device__ __forceinline__ float waveSum(float v) {
  v = dppAdd<0xB1>(v);    // quad_perm(1,0,3,2): + lane^1
  v = dppAdd<0x4E>(v);    // quad_perm(2,3,0,1): + lane^2
  v = dppAdd<0x124>(v);   // row_ror:4 : + other quad pair
  v = dppAdd<0x128>(v);   // row_ror:8 : full 16-lane row sum
  v += __shfl_xor(v, 16); // cross-row
  v += __shfl_xor(v, 32); // cross-half
  return v;
}

// ---------------------------------------------------------------------------
// kA: single HBM pass over x. grid (32, NH, B) = 4096 blocks, 256 threads.
// Block = 1024 consecutive n of one (b,h). All 16 channel float4 loads are
// issued as one independent batch into a register tile (16 KB/wave in flight
// -> latency hidden), then: logits (no max-shift: ~unit variance, fp32 exp
// safe to 88), exp, weighted sums. Merge: full 64-lane waveSum per value
// (DPP intra-row + 2 cross-row shfl); lane c keeps dK[c], lane 16+c keeps
// dQ[c], lane 32+c keeps cs[c], lanes 48/49 keep sK/sQ -> ONE coalesced
// 64-float record store per wave. xv[c] dies at merge iteration c. No LDS,
// no barriers. Biases & -mu*w cancel in softmax; sum_n attn = 1 folds mean
// subtraction into k4.
__global__ __launch_bounds__(256, 4) void kA(const float* __restrict__ x,
                                             const float* __restrict__ kw,
                                             const float* __restrict__ qw,
                                             float* __restrict__ prec) {
  const int b = blockIdx.z, h = blockIdx.y, j = blockIdx.x;
  const int t = threadIdx.x, lane = t & 63, wid = t >> 6;
  const float* xs = x + ((long)(b * C + h * CPH)) * N + (long)j * 1024 + t * 4;

  // batched independent loads -> register tile
  float4 xv[CPH];
#pragma unroll
  for (int c = 0; c < CPH; ++c) xv[c] = *(const float4*)(xs + (long)c * N);

  float4 lk = make_float4(0.f, 0.f, 0.f, 0.f);
  float4 lq = make_float4(0.f, 0.f, 0.f, 0.f);
#pragma unroll
  for (int c = 0; c < CPH; ++c) {
    const float wkc = kw[h * CPH + c], wqc = qw[h * CPH + c];
    lk.x += xv[c].x * wkc; lk.y += xv[c].y * wkc;
    lk.z += xv[c].z * wkc; lk.w += xv[c].w * wkc;
    lq.x += xv[c].x * wqc; lq.y += xv[c].y * wqc;
    lq.z += xv[c].z * wqc; lq.w += xv[c].w * wqc;
  }
  const float4 ek = make_float4(__expf(lk.x), __expf(lk.y),
                                __expf(lk.z), __expf(lk.w));
  const float4 eq = make_float4(__expf(lq.x), __expf(lq.y),
                                __expf(lq.z), __expf(lq.w));
  float sK = waveSum((ek.x + ek.y) + (ek.z + ek.w));
  float sQ = waveSum((eq.x + eq.y) + (eq.z + eq.w));

  float outv = 0.f;
#pragma unroll
  for (int c = 0; c < CPH; ++c) {
    float dk = (xv[c].x * ek.x + xv[c].y * ek.y) + (xv[c].z * ek.z + xv[c].w * ek.w);
    float dq = (xv[c].x * eq.x + xv[c].y * eq.y) + (xv[c].z * eq.z + xv[c].w * eq.w);
    float cs = (xv[c].x + xv[c].y) + (xv[c].z + xv[c].w);
    dk = waveSum(dk);   // full 64-lane sum
    dq = waveSum(dq);
    cs = waveSum(cs);
    if (lane == c)      outv = dk;
    if (lane == c + 16) outv = dq;
    if (lane == c + 32) outv = cs;
  }
  if (lane == 48) outv = sK;
  if (lane == 49) outv = sQ;

  const long pj = ((long)(b * NH + h)) * NPW + j * 4 + wid;
  prec[pj * 64 + lane] = outv;
}

// ---------------------------------------------------------------------------
// k4: combine partial records + finalize. grid(B), 512 threads (thread=channel).
__global__ __launch_bounds__(512) void k4(const float* __restrict__ prec,
                                          const float* __restrict__ pw1,
                                          const float* __restrict__ pb1,
                                          const float* __restrict__ pw2,
                                          const float* __restrict__ pb2,
                                          float* __restrict__ scale,
                                          float* __restrict__ offset,
                                          float* __restrict__ dpOut) {
  const int b = blockIdx.x;
  const int c = threadIdx.x;           // 0..511
  const int h = c >> 4, i = c & 15;
  const float* rec = prec + ((long)(b * NH + h)) * NPW * 64;

  float dk = 0.f, dq = 0.f, cs = 0.f, sk = 0.f, sq = 0.f;
  for (int j = 0; j < NPW; ++j) {
    dk += rec[j * 64 + i];
    dq += rec[j * 64 + 16 + i];
    cs += rec[j * 64 + 32 + i];
    sk += rec[j * 64 + 48];
    sq += rec[j * 64 + 49];
  }
  const float mu = cs * (1.f / N);
  const float Kv = dk / sk - mu;
  const float Qv = dq / sq - mu;

  __shared__ float muS[C], h1S[256];
  muS[c] = mu;
  __syncthreads();
  if (c < 256) {
    const int g = c >> 3;
    float a = pb1[c];
#pragma unroll
    for (int k = 0; k < 16; ++k) a += muS[g * 16 + k] * pw1[c * 16 + k];
    h1S[c] = fmaxf(a, 0.f);
  }
  __syncthreads();
  float a = pb2[c];
  const int g2 = c >> 4;
#pragma unroll
  for (int k = 0; k < 8; ++k) a += h1S[g2 * 8 + k] * pw2[c * 8 + k];
  const float P = 1.f / (1.f + __expf(-a));
  scale[b * C + c] = P;
  offset[b * C + c] = (Kv - Qv) * P;

  float p = wrs(Kv * Qv);
  __shared__ float pS[8];
  const int lane = c & 63, wid = c >> 6;
  if (lane == 0) pS[wid] = p;
  __syncthreads();
  if (c == 0) {
    float tot = 0.f;
    for (int w = 0; w < 8; ++w) tot += pS[w];
    dpOut[b] = tot * (1.f / C);
  }
}

// ---------------------------------------------------------------------------
// k5: y = x * scale[b,c] + offset[b,c]. grid (N/4096, C, B), block 256.
// y stores are nontemporal so the y stream doesn't evict x from the 256 MiB
// L3 — kA just streamed x through it, so k5's re-read can hit L3.
__global__ __launch_bounds__(256) void k5(const float* __restrict__ x,
                                          const float* __restrict__ scale,
                                          const float* __restrict__ offset,
                                          float* __restrict__ y) {
  const int b = blockIdx.z, cc = blockIdx.y;
  const int t = threadIdx.x;
  const long base = ((long)(b * C + cc)) * N + (long)blockIdx.x * 4096;
  const float s = scale[b * C + cc], o = offset[b * C + cc];
#pragma unroll
  for (int k = 0; k < 4; ++k) {
    const long i = base + (long)(k * 256 + t) * 4;
    const float4 v = *(const float4*)(x + i);
    f4v w;
    w.x = v.x * s + o; w.y = v.y * s + o;
    w.z = v.z * s + o; w.w = v.w * s + o;
    __builtin_nontemporal_store(w, (f4v*)(y + i));
  }
}

} // namespace

extern "C" void kernel_launch(void* const* d_in, const int* in_sizes, int n_in,
                              void* d_out, int out_size, void* d_ws, size_t ws_size,
                              hipStream_t stream) {
  const float* x   = (const float*)d_in[0];
  const float* pw1 = (const float*)d_in[1];
  const float* pb1 = (const float*)d_in[2];
  const float* pw2 = (const float*)d_in[3];
  const float* pb2 = (const float*)d_in[4];
  const float* kw  = (const float*)d_in[5];
  // d_in[6]=kb, d_in[8]=qb unused: biases cancel in softmax (shift-invariant),
  // and sum_n attn = 1 folds mean-subtraction into the finalize step.
  const float* qw  = (const float*)d_in[7];
  float* out = (float*)d_out;
  float* ws  = (float*)d_ws;

  // scale/offset always in ws (read by k5 while k5 writes out)
  float* scale  = ws;          // 2048
  float* offset = ws + 2048;   // 2048

  // partial records: B*NH*NPW*64 = 1,048,576 floats (4 MB)
  constexpr long PREC = (long)B * NH * NPW * 64;
  float* prec;
  if (ws_size >= (size_t)(4096 + PREC) * sizeof(float)) {
    prec = ws + 4096;
  } else {
    prec = out;  // consumed by k4 before k5 overwrites out
  }

  hipLaunchKernelGGL(kA, dim3(N / 1024, NH, B), dim3(256), 0, stream,
                     x, kw, qw, prec);
  hipLaunchKernelGGL(k4, dim3(B), dim3(C), 0, stream,
                     prec, pw1, pb1, pw2, pb2, scale, offset, out + YSIZE);
  hipLaunchKernelGGL(k5, dim3(N / 4096, C, B), dim3(256), 0, stream,
                     x, scale, offset, out);
}